// Round 1
// 225.807 us; speedup vs baseline: 1.0047x; 1.0047x over previous
//
#include <hip/hip_runtime.h>
#include <math.h>

#define B_   4
#define C_   256
#define G_   32
#define CPG  8                 // channels per group
#define N_   4096              // H*W
#define NPG  (CPG * N_)        // 32768 elements per group
#define EPS  1e-5f
#define SCALE 0.0625f          // C^-0.5 = 1/16

typedef __attribute__((ext_vector_type(8)))  __bf16 bf16x8;
typedef __attribute__((ext_vector_type(4)))  __bf16 bf16x4;
typedef __attribute__((ext_vector_type(16))) float  f32x16;

// ---------------------------------------------------------------------------
// Kernel 1a: GroupNorm partial sums (unchanged).
// ---------------------------------------------------------------------------
__global__ __launch_bounds__(256) void gn_stats_kernel(const float* __restrict__ x,
                                                       float* __restrict__ part) {
    int bid = blockIdx.x;
    int bg = bid >> 2, seg = bid & 3;
    const float4* xp4 = (const float4*)(x + (size_t)bg * NPG) + seg * 2048;
    int tid = threadIdx.x;

    float s = 0.f, ss = 0.f;
    for (int i = tid; i < 2048; i += 256) {
        float4 t = xp4[i];
        s  += t.x + t.y + t.z + t.w;
        ss += t.x * t.x + t.y * t.y + t.z * t.z + t.w * t.w;
    }
    #pragma unroll
    for (int off = 32; off; off >>= 1) {
        s  += __shfl_xor(s, off, 64);
        ss += __shfl_xor(ss, off, 64);
    }
    __shared__ float rs[2][4];
    int wave = tid >> 6, lane = tid & 63;
    if (lane == 0) { rs[0][wave] = s; rs[1][wave] = ss; }
    __syncthreads();
    if (tid == 0) {
        part[bid * 2]     = rs[0][0] + rs[0][1] + rs[0][2] + rs[0][3];
        part[bid * 2 + 1] = rs[1][0] + rs[1][1] + rs[1][2] + rs[1][3];
    }
}

// ---------------------------------------------------------------------------
// Kernel 1b: GroupNorm apply -> bf16 frag-interleaved (unchanged).
// ---------------------------------------------------------------------------
__global__ __launch_bounds__(256) void gn_apply_kernel(const float* __restrict__ x,
                                                       const float* __restrict__ w,
                                                       const float* __restrict__ bia,
                                                       const float* __restrict__ part,
                                                       __bf16* __restrict__ xnb) {
    int bid = blockIdx.x;
    int bg = bid >> 4, seg = bid & 15;
    int b = bg >> 5, g = bg & 31;
    float s  = part[(bg * 4 + 0) * 2] + part[(bg * 4 + 1) * 2]
             + part[(bg * 4 + 2) * 2] + part[(bg * 4 + 3) * 2];
    float ss = part[(bg * 4 + 0) * 2 + 1] + part[(bg * 4 + 1) * 2 + 1]
             + part[(bg * 4 + 2) * 2 + 1] + part[(bg * 4 + 3) * 2 + 1];
    float mean = s / (float)NPG;
    float var  = ss / (float)NPG - mean * mean;
    float rstd = rsqrtf(var + EPS);

    const float* xp = x + (size_t)bg * NPG;
    int n = seg * 256 + threadIdx.x;

    bf16x8 pk;
    #pragma unroll
    for (int cc = 0; cc < 8; cc++) {
        float sc = rstd * w[g * CPG + cc];
        float sh = bia[g * CPG + cc] - mean * sc;
        pk[cc] = (__bf16)(xp[(size_t)cc * N_ + n] * sc + sh);
    }
    size_t idx = ((((size_t)(b * 128 + (n >> 5)) * 16 + (g >> 1)) * 2 + (g & 1))
                  * 32 + (n & 31)) * 8;
    *(bf16x8*)(xnb + idx) = pk;
}

// ---------------------------------------------------------------------------
// Kernel 2: QKV projection, bf16 MFMA (unchanged).
// ---------------------------------------------------------------------------
__global__ __launch_bounds__(256) void qkv_kernel(const __bf16* __restrict__ xnb,
                                                  const float* __restrict__ W,
                                                  const float* __restrict__ bias,
                                                  __bf16* __restrict__ q,
                                                  __bf16* __restrict__ k,
                                                  __bf16* __restrict__ v) {
    int b = blockIdx.z, ot = blockIdx.y, nc = blockIdx.x;
    int tid = threadIdx.x, wv = tid >> 6, lane = tid & 63;
    int n31 = lane & 31, q2 = lane >> 5;
    int B0 = ot * 128 + wv * 32;

    bf16x8 wf[16];
    const float* wp = W + (size_t)(B0 + n31) * C_;
    #pragma unroll
    for (int ks = 0; ks < 16; ks++) {
        float4 t0 = *(const float4*)(wp + ks * 16 + q2 * 8);
        float4 t1 = *(const float4*)(wp + ks * 16 + q2 * 8 + 4);
        bf16x8 f;
        f[0] = (__bf16)t0.x; f[1] = (__bf16)t0.y; f[2] = (__bf16)t0.z; f[3] = (__bf16)t0.w;
        f[4] = (__bf16)t1.x; f[5] = (__bf16)t1.y; f[6] = (__bf16)t1.z; f[7] = (__bf16)t1.w;
        wf[ks] = f;
    }

    float bv[16], bvv = 0.f;
    if (ot < 4) {
        #pragma unroll
        for (int gI = 0; gI < 4; gI++)
            #pragma unroll
            for (int j = 0; j < 4; j++)
                bv[gI * 4 + j] = bias[B0 + gI * 8 + 4 * q2 + j];
    } else {
        bvv = bias[B0 + n31];
    }

    const __bf16* xb = xnb + (size_t)b * 128 * 8192;

    for (int t = 0; t < 4; t++) {
        int nt = nc * 4 + t;
        const __bf16* xg = xb + (size_t)nt * 8192 + q2 * 256 + n31 * 8;
        bf16x8 xf[16];
        #pragma unroll
        for (int ks = 0; ks < 16; ks++) xf[ks] = *(const bf16x8*)(xg + ks * 512);

        f32x16 acc;
        #pragma unroll
        for (int i = 0; i < 16; i++) acc[i] = 0.f;
        if (ot < 4) {
            #pragma unroll
            for (int ks = 0; ks < 16; ks++)
                acc = __builtin_amdgcn_mfma_f32_32x32x16_bf16(wf[ks], xf[ks], acc, 0, 0, 0);
        } else {
            #pragma unroll
            for (int ks = 0; ks < 16; ks++)
                acc = __builtin_amdgcn_mfma_f32_32x32x16_bf16(xf[ks], wf[ks], acc, 0, 0, 0);
        }

        if (ot < 4) {
            int ocb = (ot < 2) ? B0 : (B0 - 256);
            __bf16* dst = (ot < 2) ? q : k;
            bool isq = (ot < 2);
            #pragma unroll
            for (int gI = 0; gI < 4; gI++) {
                bf16x4 pk;
                #pragma unroll
                for (int j = 0; j < 4; j++) {
                    float y = acc[gI * 4 + j] + bv[gI * 4 + j];
                    if (isq) y *= SCALE;
                    pk[j] = (__bf16)y;
                }
                size_t idx = ((((size_t)(b * 128 + nt) * 16 + ((ocb >> 4) + (gI >> 1))) * 2
                               + (gI & 1)) * 32 + n31) * 8 + 4 * q2;
                *(bf16x4*)(dst + idx) = pk;
            }
        } else {
            int ocb = B0 - 512;
            #pragma unroll
            for (int gI = 0; gI < 4; gI++) {
                bf16x4 pk;
                #pragma unroll
                for (int j = 0; j < 4; j++)
                    pk[j] = (__bf16)(acc[gI * 4 + j] + bvv);
                size_t idx = (((((size_t)(b * 128 + nt) * 2 + (gI >> 1)) * 2 + (gI & 1)) * 8
                               + (ocb >> 5)) * 32 + n31) * 8 + 4 * q2;
                *(bf16x4*)(v + idx) = pk;
            }
        }
    }
}

// ---------------------------------------------------------------------------
// Kernel 3 (R12): MFMA attention, producer/consumer, 2 blocks/CU.
// Restructured: chunk = 128 keys (16 chunks). Q tile (64 rows, 32 KB) staged
// once into LDS; each producer wave owns a DISTINCT 32-key slice (kt = wid)
// and computes S^T for all 64 q-rows -> K read exactly once per block
// (kills the 2x K duplication on the L1/L2 return path). Two independent
// MFMA accumulator chains (s0/s1) per producer. Consumers pre-issue V loads
// before the barrier (latency drains there for free). Barrier count halved.
// LDS: Q 32K + P ping-pong 2x16.9K (PSTR2=132 shorts: 66 words/row -> 2-way
// bank aliasing = free) + l = 66.8 KB -> still 2 blocks/CU.
// ---------------------------------------------------------------------------
#define PSTR2 132   // p row stride in shorts (128 keys + 4 pad; 66 words)

__global__ __launch_bounds__(512, 4) void attn_kernel(const __bf16* __restrict__ q,
                                                      const __bf16* __restrict__ k,
                                                      const __bf16* __restrict__ v,
                                                      float* __restrict__ ao0,
                                                      float* __restrict__ ao1,
                                                      float* __restrict__ l0,
                                                      float* __restrict__ l1) {
    __shared__ __align__(16) __bf16 q_lds[2 * 8192];        // 32 KB, 64 q-rows
    __shared__ __align__(16) __bf16 p_lds[2][64 * PSTR2];   // 2 x 16.9 KB ping-pong P
    __shared__ float l_lds[64];

    int bid   = blockIdx.x;
    int xcd   = bid & 7;
    int b     = xcd >> 1;
    int split = xcd & 1;
    int qt    = bid >> 3;                    // 0..63, 64-row q tile
    int n0    = qt * 64;

    int tid = threadIdx.x;
    int wid = tid >> 6, lane = tid & 63;
    int n31 = lane & 31, q2 = lane >> 5;

    // Stage Q tile (2 contiguous 16 KB n-tiles) into LDS; covered by the
    // first loop barrier.
    {
        const __bf16* qsrc = q + (size_t)(b * 128 + qt * 2) * 8192;
        #pragma unroll
        for (int r = 0; r < 4; r++) {
            int e = (r * 512 + tid) * 8;
            *(bf16x8*)(q_lds + e) = *(const bf16x8*)(qsrc + e);
        }
    }
    if (tid < 64) l_lds[tid] = 0.f;

    const size_t BSTR = (size_t)N_ * C_;

    if (wid < 4) {
        // ================= PRODUCER =================
        int kt = wid;                        // distinct 32-key slice of chunk
        const __bf16* ql0 = q_lds + q2 * 256 + n31 * 8;    // rt=0; rt=1 at +8192
        const __bf16* kb0 = k + (size_t)(b * 128 + split * 64 + kt) * 8192
                            + q2 * 256 + n31 * 8;
        float l_acc0 = 0.f, l_acc1 = 0.f;

        for (int ch = 0; ch < 16; ch++) {
            __syncthreads();
            const __bf16* kg = kb0 + (size_t)ch * 32768;   // ch*4 tiles
            f32x16 s0, s1;
            #pragma unroll
            for (int i = 0; i < 16; i++) { s0[i] = 0.f; s1[i] = 0.f; }
            #pragma unroll
            for (int ks = 0; ks < 16; ks++) {
                bf16x8 kf  = *(const bf16x8*)(kg + ks * 512);
                bf16x8 qa0 = *(const bf16x8*)(ql0 + ks * 512);
                bf16x8 qa1 = *(const bf16x8*)(ql0 + 8192 + ks * 512);
                s0 = __builtin_amdgcn_mfma_f32_32x32x16_bf16(kf, qa0, s0, 0, 0, 0);
                s1 = __builtin_amdgcn_mfma_f32_32x32x16_bf16(kf, qa1, s1, 0, 0, 0);
            }
            __bf16* pbuf  = p_lds[ch & 1];
            __bf16* prow0 = pbuf + n31 * PSTR2 + kt * 32 + 4 * q2;
            __bf16* prow1 = pbuf + (32 + n31) * PSTR2 + kt * 32 + 4 * q2;
            #pragma unroll
            for (int g = 0; g < 4; g++) {
                bf16x4 pw0, pw1;
                #pragma unroll
                for (int j = 0; j < 4; j++) {
                    float p0 = __expf(s0[g * 4 + j]);
                    float p1 = __expf(s1[g * 4 + j]);
                    l_acc0 += p0; l_acc1 += p1;
                    pw0[j] = (__bf16)p0; pw1[j] = (__bf16)p1;
                }
                *(bf16x4*)(prow0 + 8 * g) = pw0;
                *(bf16x4*)(prow1 + 8 * g) = pw1;
            }
        }
        atomicAdd(&l_lds[n31], l_acc0);
        atomicAdd(&l_lds[32 + n31], l_acc1);
        __syncthreads();
        if (tid < 64) {
            float* lp = split ? l1 : l0;
            lp[(size_t)b * N_ + n0 + tid] = l_lds[tid];
        }
    } else {
        // ================= CONSUMER =================
        int cw = wid - 4;                    // owns chans [cw*64, +64)
        const __bf16* vbase = v + (size_t)b * BSTR + (size_t)split * 524288
                              + (size_t)q2 * 2048 + n31 * 8;
        f32x16 o_acc[2][2];                  // [ct][rt]
        #pragma unroll
        for (int ct = 0; ct < 2; ct++)
            #pragma unroll
            for (int rt = 0; rt < 2; rt++)
                #pragma unroll
                for (int i = 0; i < 16; i++) o_acc[ct][rt][i] = 0.f;

        for (int ch = 0; ch < 16; ch++) {
            bf16x8 vf0[8];
            if (ch > 0) {                    // pre-issue ct=0 V loads; the
                int cc = ch - 1;             // vmcnt drain at the barrier
                #pragma unroll               // lands them for free.
                for (int ks4 = 0; ks4 < 8; ks4++) {
                    size_t off = (size_t)(cc * 4 + (ks4 >> 1)) * 8192
                               + (size_t)(ks4 & 1) * 4096 + (cw * 2 + 0) * 256;
                    vf0[ks4] = *(const bf16x8*)(vbase + off);
                }
            }
            __syncthreads();
            if (ch > 0) {
                int cc = ch - 1;
                const __bf16* pbuf = p_lds[cc & 1];
                #pragma unroll
                for (int rt = 0; rt < 2; rt++) {
                    const __bf16* pb = pbuf + (rt * 32 + n31) * PSTR2 + q2 * 8;
                    #pragma unroll
                    for (int ks4 = 0; ks4 < 8; ks4++) {
                        bf16x8 pf = *(const bf16x8*)(pb + ks4 * 16);
                        o_acc[0][rt] = __builtin_amdgcn_mfma_f32_32x32x16_bf16(
                            vf0[ks4], pf, o_acc[0][rt], 0, 0, 0);
                    }
                }
                bf16x8 vf1[8];
                #pragma unroll
                for (int ks4 = 0; ks4 < 8; ks4++) {
                    size_t off = (size_t)(cc * 4 + (ks4 >> 1)) * 8192
                               + (size_t)(ks4 & 1) * 4096 + (cw * 2 + 1) * 256;
                    vf1[ks4] = *(const bf16x8*)(vbase + off);
                }
                #pragma unroll
                for (int rt = 0; rt < 2; rt++) {
                    const __bf16* pb = pbuf + (rt * 32 + n31) * PSTR2 + q2 * 8;
                    #pragma unroll
                    for (int ks4 = 0; ks4 < 8; ks4++) {
                        bf16x8 pf = *(const bf16x8*)(pb + ks4 * 16);
                        o_acc[1][rt] = __builtin_amdgcn_mfma_f32_32x32x16_bf16(
                            vf1[ks4], pf, o_acc[1][rt], 0, 0, 0);
                    }
                }
            }
        }
        // tail: consume chunk 15 from p_lds[1]
        bf16x8 vt0[8];
        #pragma unroll
        for (int ks4 = 0; ks4 < 8; ks4++) {
            size_t off = (size_t)(15 * 4 + (ks4 >> 1)) * 8192
                       + (size_t)(ks4 & 1) * 4096 + (cw * 2 + 0) * 256;
            vt0[ks4] = *(const bf16x8*)(vbase + off);
        }
        __syncthreads();
        {
            const __bf16* pbuf = p_lds[1];
            #pragma unroll
            for (int rt = 0; rt < 2; rt++) {
                const __bf16* pb = pbuf + (rt * 32 + n31) * PSTR2 + q2 * 8;
                #pragma unroll
                for (int ks4 = 0; ks4 < 8; ks4++) {
                    bf16x8 pf = *(const bf16x8*)(pb + ks4 * 16);
                    o_acc[0][rt] = __builtin_amdgcn_mfma_f32_32x32x16_bf16(
                        vt0[ks4], pf, o_acc[0][rt], 0, 0, 0);
                }
            }
            bf16x8 vt1[8];
            #pragma unroll
            for (int ks4 = 0; ks4 < 8; ks4++) {
                size_t off = (size_t)(15 * 4 + (ks4 >> 1)) * 8192
                           + (size_t)(ks4 & 1) * 4096 + (cw * 2 + 1) * 256;
                vt1[ks4] = *(const bf16x8*)(vbase + off);
            }
            #pragma unroll
            for (int rt = 0; rt < 2; rt++) {
                const __bf16* pb = pbuf + (rt * 32 + n31) * PSTR2 + q2 * 8;
                #pragma unroll
                for (int ks4 = 0; ks4 < 8; ks4++) {
                    bf16x8 pf = *(const bf16x8*)(pb + ks4 * 16);
                    o_acc[1][rt] = __builtin_amdgcn_mfma_f32_32x32x16_bf16(
                        vt1[ks4], pf, o_acc[1][rt], 0, 0, 0);
                }
            }
        }
        // fp32 partial O dump: [b][qt][cw][ct][rt][g][q2][n31][4] — coalesced.
        float* aop = split ? ao1 : ao0;
        #pragma unroll
        for (int ct = 0; ct < 2; ct++)
            #pragma unroll
            for (int rt = 0; rt < 2; rt++)
                #pragma unroll
                for (int g = 0; g < 4; g++) {
                    float4 st;
                    st.x = o_acc[ct][rt][g * 4 + 0];
                    st.y = o_acc[ct][rt][g * 4 + 1];
                    st.z = o_acc[ct][rt][g * 4 + 2];
                    st.w = o_acc[ct][rt][g * 4 + 3];
                    size_t idx = ((((((size_t)(b * 64 + qt) * 4 + cw) * 2 + ct) * 2 + rt)
                                   * 4 + g) * 2 + q2) * 128 + n31 * 4;
                    *(float4*)(aop + idx) = st;
                }
    }
}

// ---------------------------------------------------------------------------
// Kernel 4: out projection (unchanged).
// ---------------------------------------------------------------------------
__global__ __launch_bounds__(256) void proj_kernel(const float* __restrict__ ao0,
                                                   const float* __restrict__ ao1,
                                                   const float* __restrict__ l0p,
                                                   const float* __restrict__ l1p,
                                                   const float* __restrict__ W2,
                                                   const float* __restrict__ bias,
                                                   const float* __restrict__ x,
                                                   float* __restrict__ out) {
    int b = blockIdx.z, ot = blockIdx.y, nc = blockIdx.x;
    int tid = threadIdx.x, wv = tid >> 6, lane = tid & 63;
    int n31 = lane & 31, q2 = lane >> 5;
    int B0 = ot * 128 + wv * 32;

    bf16x8 wf[16];
    const float* wp = W2 + (size_t)(B0 + n31) * C_;
    #pragma unroll
    for (int ks = 0; ks < 16; ks++) {
        float4 t0 = *(const float4*)(wp + ks * 16 + q2 * 8);
        float4 t1 = *(const float4*)(wp + ks * 16 + q2 * 8 + 4);
        bf16x8 f;
        f[0] = (__bf16)t0.x; f[1] = (__bf16)t0.y; f[2] = (__bf16)t0.z; f[3] = (__bf16)t0.w;
        f[4] = (__bf16)t1.x; f[5] = (__bf16)t1.y; f[6] = (__bf16)t1.z; f[7] = (__bf16)t1.w;
        wf[ks] = f;
    }
    float bv[16];
    #pragma unroll
    for (int r = 0; r < 16; r++) bv[r] = bias[B0 + (r & 3) + 8 * (r >> 2) + 4 * q2];

    for (int t = 0; t < 4; t++) {
        int nt = nc * 4 + t;                  // 32-row tile, 0..127
        int qt = nt >> 1, rtile = nt & 1;
        int n = nt * 32 + n31;
        float inv = 1.0f / (l0p[(size_t)b * N_ + n] + l1p[(size_t)b * N_ + n]);

        bf16x8 xf[16];
        #pragma unroll
        for (int ks = 0; ks < 16; ks++) {
            int oct = ks * 2 + q2;            // chan octet 0..31
            int cw = oct >> 3, ct = (oct >> 2) & 1, ga = oct & 3;
            size_t base = ((((((size_t)(b * 64 + qt) * 4 + cw) * 2 + ct) * 2 + rtile)
                            * 4 + ga) * 2) * 128 + n31 * 4;
            float4 a0 = *(const float4*)(ao0 + base);
            float4 b0 = *(const float4*)(ao0 + base + 128);
            float4 a1 = *(const float4*)(ao1 + base);
            float4 b1 = *(const float4*)(ao1 + base + 128);
            bf16x8 f;
            f[0] = (__bf16)((a0.x + a1.x) * inv);
            f[1] = (__bf16)((a0.y + a1.y) * inv);
            f[2] = (__bf16)((a0.z + a1.z) * inv);
            f[3] = (__bf16)((a0.w + a1.w) * inv);
            f[4] = (__bf16)((b0.x + b1.x) * inv);
            f[5] = (__bf16)((b0.y + b1.y) * inv);
            f[6] = (__bf16)((b0.z + b1.z) * inv);
            f[7] = (__bf16)((b0.w + b1.w) * inv);
            xf[ks] = f;
        }

        f32x16 acc;
        #pragma unroll
        for (int i = 0; i < 16; i++) acc[i] = 0.f;
        #pragma unroll
        for (int ks = 0; ks < 16; ks++)
            acc = __builtin_amdgcn_mfma_f32_32x32x16_bf16(wf[ks], xf[ks], acc, 0, 0, 0);

        #pragma unroll
        for (int r = 0; r < 16; r++) {
            int o = B0 + (r & 3) + 8 * (r >> 2) + 4 * q2;
            size_t idx = ((size_t)(b * C_ + o)) * N_ + nt * 32 + n31;
            out[idx] = acc[r] + bv[r] + x[idx];
        }
    }
}

// ---------------------------------------------------------------------------
extern "C" void kernel_launch(void* const* d_in, const int* in_sizes, int n_in,
                              void* d_out, int out_size, void* d_ws, size_t ws_size,
                              hipStream_t stream) {
    const float* x     = (const float*)d_in[0];
    const float* gn_w  = (const float*)d_in[1];
    const float* gn_b  = (const float*)d_in[2];
    const float* qkv_w = (const float*)d_in[3];
    const float* qkv_b = (const float*)d_in[4];
    const float* out_w = (const float*)d_in[5];
    const float* out_b = (const float*)d_in[6];
    float* out = (float*)d_out;

    const size_t SZ = (size_t)B_ * C_ * N_;       // 4,194,304 elements
    char* base = (char*)d_ws;
    float*  ao0 = (float*)base;                   // 16.78 MB fp32 partial O
    float*  ao1 = (float*)(base + SZ * 4);        // 16.78 MB
    __bf16* xnb = (__bf16*)base;                  // aliases ao0 (dead by attn)
    __bf16* qb  = (__bf16*)(base + 2 * SZ * 4);   // 8.39 MB each
    __bf16* kb  = qb + SZ;
    __bf16* vb  = kb + SZ;
    float*  l0  = (float*)(base + 2 * SZ * 4 + 3 * SZ * 2);  // [B,N] fp32
    float*  l1  = l0 + B_ * N_;
    float*  part = l1 + B_ * N_;                  // [512][2] GN partials

    gn_stats_kernel<<<dim3(512), 256, 0, stream>>>(x, part);
    gn_apply_kernel<<<dim3(2048), 256, 0, stream>>>(x, gn_w, gn_b, part, xnb);
    qkv_kernel<<<dim3(32, 6, B_), 256, 0, stream>>>(xnb, qkv_w, qkv_b, qb, kb, vb);
    attn_kernel<<<dim3(512), 512, 0, stream>>>(qb, kb, vb, ao0, ao1, l0, l1);
    proj_kernel<<<dim3(32, 2, B_), 256, 0, stream>>>(ao0, ao1, l0, l1, out_w, out_b, x, out);
}